// Round 5
// baseline (121.377 us; speedup 1.0000x reference)
//
#include <hip/hip_runtime.h>

// Fused 79x69 box-filter mean + (x - mean)/5, SAME zero padding.
// One kernel: per-block 32x128 output tile; vertical sliding sums into LDS,
// horizontal 69-tap window via float4 chunked prefix arithmetic from LDS.

#define HH   512
#define WW   512
#define NIMG 32
#define RH   39            // (79-1)/2
#define RW   34            // (69-1)/2
#define TH   32
#define TW   128
#define HALOC (TW + 2*RW)  // 196 colsum columns per tile
#define LDSC  204          // row stride; 204 % 32 == 12 -> optimal b128 bank spread

__device__ __forceinline__ float hsum4(float4 v) { return (v.x + v.y) + (v.z + v.w); }

__global__ __launch_bounds__(256) void fused_kernel(const float* __restrict__ x,
                                                    float* __restrict__ out) {
    __shared__ float cs[TH][LDSC];

    int b   = blockIdx.x;
    int n   = b >> 6;            // 64 tiles per image (16 x 4)
    int rem = b & 63;
    int th  = rem >> 2;          // 0..15
    int tw  = rem & 3;           // 0..3
    int h0  = th * TH;
    int w0  = tw * TW;
    int tid = threadIdx.x;

    const float* img = x + (size_t)n * HH * WW;

    // ---------------- Phase 1: vertical 79-tap sliding colsum -> LDS -------
    if (tid < HALOC) {
        int gw = w0 - RW + tid;                 // global column, may be OOB
        if (gw >= 0 && gw < WW) {
            const float* p = img + gw;
            if (h0 >= RH && h0 + TH + RH < HH) {
                // interior tile: rows h0-39 .. h0+71 all valid, branch-free
                const float* pr = p + (size_t)(h0 - RH) * WW;
                float s0 = 0, s1 = 0, s2 = 0, s3 = 0;
                #pragma unroll
                for (int i = 0; i < 76; i += 4) {
                    s0 += pr[(size_t)(i + 0) * WW];
                    s1 += pr[(size_t)(i + 1) * WW];
                    s2 += pr[(size_t)(i + 2) * WW];
                    s3 += pr[(size_t)(i + 3) * WW];
                }
                s0 += pr[(size_t)76 * WW];
                s1 += pr[(size_t)77 * WW];
                s2 += pr[(size_t)78 * WW];
                float s = (s0 + s1) + (s2 + s3);
                #pragma unroll 4
                for (int r = 0; r < TH; ++r) {
                    cs[r][tid] = s;
                    s += p[(size_t)(h0 + r + RH + 1) * WW];
                    s -= p[(size_t)(h0 + r - RH) * WW];
                }
            } else {
                // border tile (top/bottom): clamped window
                int lo = h0 - RH; if (lo < 0) lo = 0;
                int hi = h0 + RH; if (hi > HH - 1) hi = HH - 1;
                float s0 = 0, s1 = 0, s2 = 0, s3 = 0;
                int i = lo;
                for (; i + 4 <= hi + 1; i += 4) {
                    s0 += p[(size_t)(i + 0) * WW];
                    s1 += p[(size_t)(i + 1) * WW];
                    s2 += p[(size_t)(i + 2) * WW];
                    s3 += p[(size_t)(i + 3) * WW];
                }
                for (; i <= hi; ++i) s0 += p[(size_t)i * WW];
                float s = (s0 + s1) + (s2 + s3);
                for (int r = 0; r < TH; ++r) {
                    cs[r][tid] = s;
                    int ia = h0 + r + RH + 1, ib = h0 + r - RH;
                    if (ia < HH)  s += p[(size_t)ia * WW];
                    if (ib >= 0)  s -= p[(size_t)ib * WW];
                }
            }
        } else {
            // zero padding: columns outside the image contribute 0
            #pragma unroll 4
            for (int r = 0; r < TH; ++r) cs[r][tid] = 0.0f;
        }
    }
    __syncthreads();

    // ---------------- Phase 2: horizontal 69-tap window + finalize ---------
    const float INV = 1.0f / (79.0f * 69.0f);
    int row = tid >> 3;          // 0..31
    int seg = tid & 7;           // 0..7, 16 outputs each
    int c0  = seg * 16;

    const float4* cp  = (const float4*)(&cs[row][0] + c0);   // 16B-aligned
    const float4* xp4 = (const float4*)(img + (size_t)(h0 + row) * WW + (w0 + c0));
    float4*       op4 = (float4*)(out + (size_t)n * HH * WW
                                      + (size_t)(h0 + row) * WW + (w0 + c0));

    // x loads issued early: latency hides under the LDS prologue
    float4 xi0 = xp4[0], xi1 = xp4[1], xi2 = xp4[2], xi3 = xp4[3];

    // T = sum of colsum cols [c0, c0+67]  (17 aligned float4 chunks)
    float4 t4 = make_float4(0, 0, 0, 0), u4 = make_float4(0, 0, 0, 0);
    #pragma unroll
    for (int i = 0; i < 16; i += 2) {
        float4 a = cp[i], bq = cp[i + 1];
        t4.x += a.x;  t4.y += a.y;  t4.z += a.z;  t4.w += a.w;
        u4.x += bq.x; u4.y += bq.y; u4.z += bq.z; u4.w += bq.w;
    }
    float T = hsum4(t4) + hsum4(u4) + hsum4(cp[16]);

    float4 xin[4] = { xi0, xi1, xi2, xi3 };
    #pragma unroll
    for (int g = 0; g < 4; ++g) {
        float4 vin  = cp[17 + g];   // incoming cols c0+68+4g ..
        float4 vout = cp[g];        // outgoing cols c0+4g ..
        float pin0 = vin.x;
        float pin1 = pin0 + vin.y;
        float pin2 = pin1 + vin.z;
        float pin3 = pin2 + vin.w;
        float po0 = vout.x;
        float po1 = po0 + vout.y;
        float po2 = po1 + vout.z;
        float po3 = po2 + vout.w;

        float4 xi = xin[g];
        float4 o;
        o.x = (xi.x - (T + pin0)       * INV) * 0.2f;
        o.y = (xi.y - (T + pin1 - po0) * INV) * 0.2f;
        o.z = (xi.z - (T + pin2 - po1) * INV) * 0.2f;
        o.w = (xi.w - (T + pin3 - po2) * INV) * 0.2f;
        op4[g] = o;

        T += pin3 - po3;            // slide window by 4
    }
}

extern "C" void kernel_launch(void* const* d_in, const int* in_sizes, int n_in,
                              void* d_out, int out_size, void* d_ws, size_t ws_size,
                              hipStream_t stream) {
    const float* x   = (const float*)d_in[0];
    float*       out = (float*)d_out;

    int nblocks = NIMG * (HH / TH) * (WW / TW);   // 32 * 16 * 4 = 2048
    fused_kernel<<<nblocks, 256, 0, stream>>>(x, out);
}